// Round 1
// 965.918 us; speedup vs baseline: 1.1508x; 1.1508x over previous
//
#include <hip/hip_runtime.h>
#include <math.h>

#define BATCH 1024
#define NSLOT 128
#define DDIM  512
#define BB 4  // batch rows per k_prep block

__device__ __forceinline__ float sigmoidf_(float x) { return 1.0f / (1.0f + expf(-x)); }
__device__ __forceinline__ float clip01(float x) { return fminf(fmaxf(x, 0.0f), 1.0f); }
__device__ __forceinline__ float dot4(float4 a, float4 b) {
    return fmaf(a.x, b.x, fmaf(a.y, b.y, fmaf(a.z, b.z, a.w * b.w)));
}

// Kernel 1: fused candidate GEMM (ck = tanh(h@Wk+bk), cv = tanh(h@Wv+bv)) +
// all per-b scalar projections (wr/im/mg/bd) + 1/||ck||.
// grid BATCH/BB, block 512 (one thread per output column).
__global__ __launch_bounds__(512) void k_prep(
    const float* __restrict__ hidden,
    const float* __restrict__ Wk, const float* __restrict__ bk,
    const float* __restrict__ Wv, const float* __restrict__ bv,
    const float* __restrict__ Wwr, const float* __restrict__ bwr,
    const float* __restrict__ Wmg, const float* __restrict__ bmg,
    const float* __restrict__ Wbd, const float* __restrict__ bbd,
    const float* __restrict__ Wim, const float* __restrict__ bim,
    float* __restrict__ ck, float* __restrict__ cv, float* __restrict__ scal)
{
    __shared__ __align__(16) float hs[BB][DDIM];
    __shared__ float sred[8][BB * 5];
    const int b0 = blockIdx.x * BB;
    const int c  = threadIdx.x;          // 0..511

    {   // stage BB rows of hidden (BB*DDIM = 2048 floats = 512 float4)
        const float4* h4 = (const float4*)(hidden + (size_t)b0 * DDIM);
        ((float4*)&hs[0][0])[c] = h4[c];
    }
    __syncthreads();

    float ak[BB] = {0.f, 0.f, 0.f, 0.f}, av[BB] = {0.f, 0.f, 0.f, 0.f};
#pragma unroll 4
    for (int e = 0; e < DDIM; ++e) {
        const float wk = Wk[(size_t)e * DDIM + c];
        const float wv = Wv[(size_t)e * DDIM + c];
#pragma unroll
        for (int bb = 0; bb < BB; ++bb) {
            const float h = hs[bb][e];   // wave-broadcast LDS read
            ak[bb] = fmaf(h, wk, ak[bb]);
            av[bb] = fmaf(h, wv, av[bb]);
        }
    }

    const float bkc = bk[c], bvc = bv[c];
    const float wwr = Wwr[c], wmg = Wmg[c], wbd = Wbd[c], wim = Wim[c];
    float p[BB * 5];
#pragma unroll
    for (int bb = 0; bb < BB; ++bb) {
        const float k = tanhf(ak[bb] + bkc);
        const float v = tanhf(av[bb] + bvc);
        ck[(size_t)(b0 + bb) * DDIM + c] = k;
        cv[(size_t)(b0 + bb) * DDIM + c] = v;
        const float h = hs[bb][c];
        p[bb * 5 + 0] = h * wwr;
        p[bb * 5 + 1] = h * wim;
        p[bb * 5 + 2] = h * wmg;
        p[bb * 5 + 3] = h * wbd;
        p[bb * 5 + 4] = k * k;           // ||ck||^2 partial
    }
#pragma unroll
    for (int off = 32; off > 0; off >>= 1)
#pragma unroll
        for (int j = 0; j < BB * 5; ++j) p[j] += __shfl_down(p[j], off, 64);

    const int wave = threadIdx.x >> 6, lane = threadIdx.x & 63;
    if (lane == 0)
#pragma unroll
        for (int j = 0; j < BB * 5; ++j) sred[wave][j] = p[j];
    __syncthreads();

    if (threadIdx.x < BB * 5) {
        float s = 0.f;
#pragma unroll
        for (int w = 0; w < 8; ++w) s += sred[w][threadIdx.x];
        const int bb = threadIdx.x / 5, st = threadIdx.x % 5;
        float outv;
        if      (st == 0) outv = sigmoidf_(s + bwr[0]);            // write_strength
        else if (st == 1) outv = sigmoidf_(s + bim[0]);            // importance
        else if (st == 2) outv = s + bmg[0];                       // merge logit part
        else if (st == 3) outv = s + bbd[0];                       // bind logit part
        else              outv = 1.0f / fmaxf(sqrtf(s), 1e-6f);    // 1/max(||ck||,eps)
        scal[(b0 + bb) * 5 + st] = outv;
    }
}

// Kernel 2: fused stream + reduce + gate + fixup. One block per batch b.
// 8 waves x 16 rows each: copy rows to outputs while computing the 5 per-row
// dot-reductions; then in-block argmax, gating, protection, and the single
// target-row blend. Zero intermediate global round-trips.
__global__ __launch_bounds__(512) void k_main(
    const float* __restrict__ wkeys, const float* __restrict__ wvals,
    const float* __restrict__ wprot, const float* __restrict__ wusage,
    const float* __restrict__ wage,
    const float* __restrict__ ck, const float* __restrict__ cv,
    const float* __restrict__ scal,
    const float* __restrict__ Woc, const float* __restrict__ boc,
    const float* __restrict__ Wpr, const float* __restrict__ bpr,
    float* __restrict__ out_keys, float* __restrict__ out_vals,
    float* __restrict__ out_prot, float* __restrict__ out_wstr,
    float* __restrict__ out_mpref, float* __restrict__ out_bstr,
    float* __restrict__ out_ovmean, float* __restrict__ out_pmean,
    float* __restrict__ out_msim, float* __restrict__ out_ovr)
{
    const int b = blockIdx.x;
    const int wave = threadIdx.x >> 6, lane = threadIdx.x & 63;
    const int tid = threadIdx.x;
    __shared__ float s_sim[NSLOT], s_occ[NSLOT], s_ep[NSLOT], s_rs[NSLOT],
                     s_eu[NSLOT], s_ea[NSLOT], s_up[NSLOT];
    __shared__ float s_prot[NSLOT], s_usage[NSLOT], s_age[NSLOT];
    __shared__ int s_idx[2];

    const size_t rowbase = (size_t)b * NSLOT;
    if (tid < NSLOT) {                       // coalesced preload of per-row scalars
        s_prot[tid]  = wprot[rowbase + tid];
        s_usage[tid] = wusage[rowbase + tid];
        s_age[tid]   = wage[rowbase + tid];
    }

    // per-wave constant vectors (L2/L1-hot)
    const float4* c4  = (const float4*)(ck + (size_t)b * DDIM);
    const float4 c0 = c4[lane],  c1 = c4[lane + 64];
    const float4* oc4 = (const float4*)Woc;
    const float4 o0 = oc4[lane], o1 = oc4[lane + 64];
    const float4* pr4 = (const float4*)Wpr;
    const float4 q0 = pr4[lane], q1 = pr4[lane + 64];
    const float inv_ck = scal[b * 5 + 4];
    const float boc0 = boc[0], bpr0 = bpr[0];
    __syncthreads();

    // Phase 1: stream 16 rows per wave (copy + reductions)
    for (int i = 0; i < 16; ++i) {
        const int n = wave * 16 + i;
        const size_t r = rowbase + n;
        const float4* k4 = (const float4*)wkeys + r * (DDIM / 4);
        const float4* v4 = (const float4*)wvals + r * (DDIM / 4);
        float4* ok4 = (float4*)out_keys + r * (DDIM / 4);
        float4* ov4 = (float4*)out_vals + r * (DDIM / 4);
        const float4 k0 = k4[lane], k1 = k4[lane + 64];
        const float4 v0 = v4[lane], v1 = v4[lane + 64];
        ok4[lane] = k0; ok4[lane + 64] = k1;
        ov4[lane] = v0; ov4[lane + 64] = v1;
        float dk  = dot4(k0, c0) + dot4(k1, c1);
        float kk  = dot4(k0, k0) + dot4(k1, k1);
        float vv  = dot4(v0, v0) + dot4(v1, v1);
        float doc = dot4(v0, o0) + dot4(v1, o1);
        float dpr = dot4(v0, q0) + dot4(v1, q1);
#pragma unroll
        for (int off = 32; off > 0; off >>= 1) {
            dk  += __shfl_down(dk, off, 64);
            kk  += __shfl_down(kk, off, 64);
            vv  += __shfl_down(vv, off, 64);
            doc += __shfl_down(doc, off, 64);
            dpr += __shfl_down(dpr, off, 64);
        }
        if (lane == 0) {
            const float sim  = dk * inv_ck * (1.0f / fmaxf(sqrtf(kk), 1e-6f));
            const float nocc = clip01(sqrtf(vv) * 0.04419417382415922f);  // /sqrt(512)
            const float occ  = clip01(0.5f * sigmoidf_(doc + boc0) + 0.5f * nocc);
            const float ep   = clip01(0.4f * sigmoidf_(dpr + bpr0) + 0.6f * s_prot[n]);
            const float eu   = clip01(0.5f * occ + 0.5f * s_usage[n]);
            const float ea   = clip01(s_age[n]);
            s_sim[n] = sim; s_occ[n] = occ; s_ep[n] = ep; s_eu[n] = eu; s_ea[n] = ea;
            s_rs[n]  = 1.15f * (1.f - occ) + 0.85f * (1.f - ep) + 0.65f * ea
                     + 0.45f * (1.f - eu) + 0.25f * (1.f - sim);
        }
    }
    __syncthreads();

    // Phase 2: parallel argmax (first-index tie-break == jnp.argmax).
    // wave0 -> sim, wave1 -> rs.
    if (wave < 2) {
        const float* arr = (wave == 0) ? s_sim : s_rs;
        float v = arr[lane]; int idx = lane;
        const float v2 = arr[lane + 64];
        if (v2 > v) { v = v2; idx = lane + 64; }
#pragma unroll
        for (int off = 32; off > 0; off >>= 1) {
            const float ovv = __shfl_down(v, off, 64);
            const int   oii = __shfl_down(idx, off, 64);
            if (ovv > v || (ovv == v && oii < idx)) { v = ovv; idx = oii; }
        }
        if (lane == 0) s_idx[wave] = idx;
    }
    __syncthreads();

    // Phase 3: gating scalars (computed redundantly; all from LDS/L1)
    const int mi = s_idx[0], ri = s_idx[1];
    const float max_sim = s_sim[mi];
    const float wstr = scal[b * 5 + 0];
    const float imv  = scal[b * 5 + 1];
    const float mgl  = scal[b * 5 + 2];
    const float bdl  = scal[b * 5 + 3];
    const float mpref = sigmoidf_(mgl + 2.4f * max_sim + 1.6f * (s_occ[mi] - 0.5f)
                                  + 1.0f * (s_eu[mi] - 0.5f) - 0.8f * s_ea[mi]);
    const bool use_merge = (mpref >= 0.5f) && (max_sim > 0.55f) && (s_occ[mi] > 0.35f);
    const int target = use_merge ? mi : ri;
    const float bstr = sigmoidf_(bdl + 2.2f * max_sim);
    const float conflict_t = clip01(1.f - s_sim[target]);
    const float ov = (0.15f + 0.85f * wstr) * (1.f - 0.65f * s_ep[target] * conflict_t);

    if (tid < NSLOT) {
        const size_t r = rowbase + tid;
        const float ovn = (tid == target) ? ov : 0.f;
        out_ovr[r] = ovn;
        const float up = clip01(s_prot[tid] * 0.98f + ovn * (0.5f + 0.5f * imv));
        out_prot[r] = up;
        s_up[tid] = up;
    }
    __syncthreads();

    if (wave == 0) {
        float s = s_up[lane] + s_up[lane + 64];
#pragma unroll
        for (int off = 32; off > 0; off >>= 1) s += __shfl_down(s, off, 64);
        if (lane == 0) {
            out_wstr[b]   = wstr;
            out_mpref[b]  = mpref;
            out_bstr[b]   = bstr;
            out_ovmean[b] = ov * (1.0f / NSLOT);
            out_pmean[b]  = s * (1.0f / NSLOT);
            out_msim[b]   = max_sim;
        }
    }

    // Phase 4: target-row blend (128 threads x one float4). Overwrites the
    // copy written in phase 1 (ordered by the barriers above).
    if (tid < NSLOT) {
        const float kmix = use_merge ? (0.22f + 0.38f * bstr) : (0.78f + 0.18f * bstr);
        const float vmix = use_merge ? (0.45f + 0.35f * imv)  : (0.75f + 0.20f * imv);
        const float fk = ov * kmix;
        const float fv = ov * vmix;
        const size_t base = (rowbase + target) * DDIM;
        const float4 k = ((const float4*)(wkeys + base))[tid];
        const float4 c = ((const float4*)(ck + (size_t)b * DDIM))[tid];
        const float4 v = ((const float4*)(wvals + base))[tid];
        const float4 w = ((const float4*)(cv + (size_t)b * DDIM))[tid];
        float4 nk, nv;
        nk.x = fmaf(fk, c.x - k.x, k.x); nk.y = fmaf(fk, c.y - k.y, k.y);
        nk.z = fmaf(fk, c.z - k.z, k.z); nk.w = fmaf(fk, c.w - k.w, k.w);
        nv.x = fmaf(fv, w.x - v.x, v.x); nv.y = fmaf(fv, w.y - v.y, v.y);
        nv.z = fmaf(fv, w.z - v.z, v.z); nv.w = fmaf(fv, w.w - v.w, v.w);
        ((float4*)(out_keys + base))[tid] = nk;
        ((float4*)(out_vals + base))[tid] = nv;
    }
}

extern "C" void kernel_launch(void* const* d_in, const int* in_sizes, int n_in,
                              void* d_out, int out_size, void* d_ws, size_t ws_size,
                              hipStream_t stream)
{
    (void)in_sizes; (void)n_in; (void)out_size; (void)ws_size;

    const float* hidden = (const float*)d_in[0];
    const float* wkeys  = (const float*)d_in[1];
    const float* wvals  = (const float*)d_in[2];
    const float* wprot  = (const float*)d_in[3];
    const float* wusage = (const float*)d_in[4];
    const float* wage   = (const float*)d_in[5];
    const float* Wk  = (const float*)d_in[6];
    const float* bk  = (const float*)d_in[7];
    const float* Wv  = (const float*)d_in[8];
    const float* bv  = (const float*)d_in[9];
    const float* Wwr = (const float*)d_in[10];
    const float* bwr = (const float*)d_in[11];
    const float* Wmg = (const float*)d_in[12];
    const float* bmg = (const float*)d_in[13];
    const float* Wbd = (const float*)d_in[14];
    const float* bbd = (const float*)d_in[15];
    const float* Wim = (const float*)d_in[16];
    const float* bim = (const float*)d_in[17];
    const float* Woc = (const float*)d_in[18];
    const float* boc = (const float*)d_in[19];
    const float* Wpr = (const float*)d_in[20];
    const float* bpr = (const float*)d_in[21];

    float* out = (float*)d_out;
    const size_t BND = (size_t)BATCH * NSLOT * DDIM;   // 67,108,864
    const size_t BN  = (size_t)BATCH * NSLOT;          // 131,072
    float* out_keys   = out;
    float* out_vals   = out_keys + BND;
    float* out_prot   = out_vals + BND;
    float* out_wstr   = out_prot + BN;
    float* out_mpref  = out_wstr + BATCH;
    float* out_bstr   = out_mpref + BATCH;
    float* out_ovmean = out_bstr + BATCH;
    float* out_pmean  = out_ovmean + BATCH;
    float* out_msim   = out_pmean + BATCH;
    float* out_ovr    = out_msim + BATCH;

    float* ws   = (float*)d_ws;
    float* ck   = ws;                                  // B*D
    float* cv   = ck + (size_t)BATCH * DDIM;           // B*D
    float* scal = cv + (size_t)BATCH * DDIM;           // B*5

    k_prep<<<dim3(BATCH / BB), 512, 0, stream>>>(
        hidden, Wk, bk, Wv, bv, Wwr, bwr, Wmg, bmg, Wbd, bbd, Wim, bim,
        ck, cv, scal);
    k_main<<<dim3(BATCH), 512, 0, stream>>>(
        wkeys, wvals, wprot, wusage, wage, ck, cv, scal, Woc, boc, Wpr, bpr,
        out_keys, out_vals, out_prot, out_wstr, out_mpref, out_bstr,
        out_ovmean, out_pmean, out_msim, out_ovr);
}